// Round 1
// baseline (264.216 us; speedup 1.0000x reference)
//
#include <hip/hip_runtime.h>
#include <math.h>

// Problem constants
#define Hc 384
#define Wc 512
#define Bc 4
#define NP 12
#define HWc (Hc * Wc)        // 196608
#define Pc (Bc * HWc)        // 786432
#define MAX_FLOW_C 443.40500673763256f   // sqrt(384*512)
#define LOG2_C 0.69314718055994530942f   // ln(2)
#define L2E_C  1.44269504088896340736f   // log2(e)

// Occupancy-oriented re-chunk: 3 chunks x 4 steps (was 2 x 6).
// Per-thread load payload: 4 steps * 5 vf4 + 3 vf4 (gt/valid) = 23 vf4
// (~92 VGPRs) -> fits the 128-VGPR budget of 4 waves/SIMD, pinned via
// __launch_bounds__(256, 4). Extra cost: gt/valid fetched 3x instead of
// 2x (+9.4 MB, ~+1.4 us) — they stay L2-resident since fp/ip streams are
// nontemporal and bypass L2.
#define NCH 3    // step chunks (blockIdx.y)
#define NSPC 4   // steps per chunk (NCH*NSPC == NP)
#define NBG 768  // pixel-group blocks (Pc/4/256)
#define NQ 25    // 12 sums + 12 counts + mask-count

typedef float vf4 __attribute__((ext_vector_type(4)));

__device__ __forceinline__ float fexp2(float x) {
#if __has_builtin(__builtin_amdgcn_exp2f)
    return __builtin_amdgcn_exp2f(x);
#else
    return exp2f(x);
#endif
}
__device__ __forceinline__ float flog2(float x) {
#if __has_builtin(__builtin_amdgcn_logf)
    return __builtin_amdgcn_logf(x);   // v_log_f32 = log2
#else
    return log2f(x);
#endif
}

// logsumexp in base-2 units: lse22(a,b) = log2(2^a + 2^b)
__device__ __forceinline__ float lse22(float a, float b) {
    float m = fmaxf(a, b);
    float d = fminf(a, b) - m;   // <= 0
    return m + flog2(1.0f + fexp2(d));
}

// Streaming one-touch loads (L3 is evicted by the harness's ws poison fill
// anyway; nt keeps the stream out of L2 so gt/valid lines survive).
__device__ __forceinline__ vf4 ldnt4(const float* p) {
    return __builtin_nontemporal_load((const vf4*)p);
}

// Stage 1: per-block partials, NO atomics. part[q * NBG + gb], q in [0, NQ).
__global__ __launch_bounds__(256, 4) void loss_part(
    const float* __restrict__ fp,     // (12,4,2,H,W)
    const float* __restrict__ ip,     // (12,4,4,H,W)
    const float* __restrict__ gt,     // (4,2,H,W)
    const float* __restrict__ valid,  // (4,1,H,W)
    float* __restrict__ part) {

    const int chunk = blockIdx.y;                   // 0..NCH-1
    const int gb    = blockIdx.x;                   // 0..NBG-1
    const int g  = gb * 256 + threadIdx.x;          // float4-group id, exact cover
    const int b  = g / (HWc / 4);
    const int hw = (g % (HWc / 4)) * 4;
    const int n0 = chunk * NSPC;

    const vf4 gx4 = *(const vf4*)(gt + ((size_t)b * 2 + 0) * HWc + hw);
    const vf4 gy4 = *(const vf4*)(gt + ((size_t)b * 2 + 1) * HWc + hw);
    const vf4 vv4 = *(const vf4*)(valid + (size_t)b * HWc + hw);

    float gxa[4] = {gx4.x, gx4.y, gx4.z, gx4.w};
    float gya[4] = {gy4.x, gy4.y, gy4.z, gy4.w};
    float vva[4] = {vv4.x, vv4.y, vv4.z, vv4.w};

    bool  m1[4];
    float mcnt = 0.0f;
#pragma unroll
    for (int j = 0; j < 4; ++j) {
        float mag = sqrtf(gxa[j] * gxa[j] + gya[j] * gya[j]);
        m1[j] = (mag < MAX_FLOW_C) && (vva[j] != 0.0f);
        mcnt += m1[j] ? 1.0f : 0.0f;
    }

    float s[NSPC];
    float c[NSPC];
#pragma unroll
    for (int k = 0; k < NSPC; ++k) { s[k] = 0.0f; c[k] = 0.0f; }

#pragma unroll
    for (int k = 0; k < NSPC; ++k) {
        const int n = n0 + k;
        const float* fbase = fp + ((size_t)(n * Bc + b) * 2) * HWc + hw;
        const float* ibase = ip + ((size_t)(n * Bc + b) * 4) * HWc + hw;

        const vf4 fx4 = ldnt4(fbase);
        const vf4 fy4 = ldnt4(fbase + HWc);
        const vf4 a04 = ldnt4(ibase);
        const vf4 a14 = ldnt4(ibase + HWc);
        const vf4 lb4 = ldnt4(ibase + 2 * (size_t)HWc);
        // info channel 3 never read: clip(x, 0, 0) == 0 identically.

        float fxa[4] = {fx4.x, fx4.y, fx4.z, fx4.w};
        float fya[4] = {fy4.x, fy4.y, fy4.z, fy4.w};
        float a0a[4] = {a04.x, a04.y, a04.z, a04.w};
        float a1a[4] = {a14.x, a14.y, a14.z, a14.w};
        float lba[4] = {lb4.x, lb4.y, lb4.z, lb4.w};

#pragma unroll
        for (int j = 0; j < 4; ++j) {
            // Base-2 units: X' = X*log2(e); nf = ln2 * nf'.
            float LB  = fminf(fmaxf(lba[j], 0.0f), 10.0f) * L2E_C;
            float e2  = fexp2(-LB);             // exp(-lb0), unscaled
            float A0  = a0a[j] * L2E_C;
            float A1  = a1a[j] * L2E_C;
            float lsa = lse22(A0, A1);
            float t10 = A0 - 1.0f - LB;
            float t11 = A1 - 1.0f;              // lb1 == 0
            float D0  = fabsf(gxa[j] - fxa[j]) * L2E_C;
            float D1  = fabsf(gya[j] - fya[j]) * L2E_C;

            float nf0 = lsa - lse22(t10 - D0 * e2, t11 - D0);
            float nf1 = lsa - lse22(t10 - D1 * e2, t11 - D1);

            bool ok0 = m1[j] && isfinite(nf0);
            bool ok1 = m1[j] && isfinite(nf1);
            s[k] += ok0 ? nf0 : 0.0f;
            c[k] += ok0 ? 1.0f : 0.0f;
            s[k] += ok1 ? nf1 : 0.0f;
            c[k] += ok1 ? 1.0f : 0.0f;
        }
    }

    // ---- reduction: wave shuffle -> LDS -> plain stores (no atomics) ----
#pragma unroll
    for (int k = 0; k < NSPC; ++k) {
        for (int off = 32; off > 0; off >>= 1) {
            s[k] += __shfl_down(s[k], off);
            c[k] += __shfl_down(c[k], off);
        }
    }
    for (int off = 32; off > 0; off >>= 1) mcnt += __shfl_down(mcnt, off);

    __shared__ float red[4][2 * NSPC + 1];
    const int lane = threadIdx.x & 63;
    const int wid  = threadIdx.x >> 6;
    if (lane == 0) {
#pragma unroll
        for (int k = 0; k < NSPC; ++k) {
            red[wid][k]        = s[k];
            red[wid][NSPC + k] = c[k];
        }
        red[wid][2 * NSPC] = mcnt;
    }
    __syncthreads();
    if (threadIdx.x < 2 * NSPC + 1) {
        float v = red[0][threadIdx.x] + red[1][threadIdx.x] +
                  red[2][threadIdx.x] + red[3][threadIdx.x];
        int q;
        if (threadIdx.x < NSPC)           q = n0 + threadIdx.x;             // sums 0..11
        else if (threadIdx.x < 2 * NSPC)  q = 12 + n0 + threadIdx.x - NSPC; // counts 12..23
        else                              q = 24;                           // mcnt
        if (q != 24 || chunk == 0)        // q=24 written by chunk-0 blocks only
            part[(size_t)q * NBG + gb] = v;
    }
    // Every part[] slot is written every launch -> no zero-init needed.
}

// Stage 2+3 fused: one block reduces 25 x 768 partials and assembles the loss.
// Each wave owns q = wid, wid+8, ... ; lane-strided loads hit L2 (part was
// just written). Saves one dispatch vs the previous reduce+final pair.
__global__ __launch_bounds__(512) void loss_tail(
    const float* __restrict__ part, float* __restrict__ out) {
    __shared__ float sq[NQ];
    const int lane = threadIdx.x & 63;
    const int wid  = threadIdx.x >> 6;   // 0..7
    for (int q = wid; q < NQ; q += 8) {
        const float* p = part + (size_t)q * NBG;
        float v = 0.0f;
        for (int i = lane; i < NBG; i += 64) v += p[i];   // 12 iters
        for (int off = 32; off > 0; off >>= 1) v += __shfl_down(v, off);
        if (lane == 0) sq[q] = v;
    }
    __syncthreads();
    if (threadIdx.x == 0) {
        float loss = 0.0f;
#pragma unroll
        for (int n = 0; n < NP; ++n)
            loss += LOG2_C * sq[n] / fmaxf(sq[12 + n], 1.0f);
        float mean_mask = sq[24] / (float)Pc;
        out[0] = (mean_mask < 0.25f) ? 0.0f : loss;
    }
}

extern "C" void kernel_launch(void* const* d_in, const int* in_sizes, int n_in,
                              void* d_out, int out_size, void* d_ws, size_t ws_size,
                              hipStream_t stream) {
    const float* fp    = (const float*)d_in[0];
    const float* ip    = (const float*)d_in[1];
    const float* gt    = (const float*)d_in[2];
    const float* valid = (const float*)d_in[3];
    float* part = (float*)d_ws;                    // NQ * NBG floats

    loss_part<<<dim3(NBG, NCH), 256, 0, stream>>>(fp, ip, gt, valid, part);
    loss_tail<<<1, 512, 0, stream>>>(part, (float*)d_out);
}

// Round 2
// 253.422 us; speedup vs baseline: 1.0426x; 1.0426x over previous
//
#include <hip/hip_runtime.h>
#include <math.h>

// Problem constants
#define Hc 384
#define Wc 512
#define Bc 4
#define NP 12
#define HWc (Hc * Wc)        // 196608
#define Pc (Bc * HWc)        // 786432
#define MAX_FLOW_C 443.40500673763256f   // sqrt(384*512)
#define LOG2_C 0.69314718055994530942f   // ln(2)
#define L2E_C  1.44269504088896340736f   // log2(e)

// R1 post-mortem: the 3x4 re-chunk + __launch_bounds__(256,4) regressed
// +18us (likely VGPR spill from the 128-reg cap; occupancy was never the
// limiter -- 12 waves/CU x ~10 outstanding 1KB loads already covers 900cy
// HBM latency).  Reverted to the known-good 2x6 layout, compiler-chosen
// register count.
#define NCH 2    // step chunks (blocks per pixel-group)
#define NSPC 6   // steps per chunk (NCH*NSPC == NP)
#define NBG 768  // pixel-group blocks (Pc/4/256)
#define NQ 25    // 12 sums + 12 counts + mask-count

typedef float vf4 __attribute__((ext_vector_type(4)));

__device__ __forceinline__ float fexp2(float x) {
#if __has_builtin(__builtin_amdgcn_exp2f)
    return __builtin_amdgcn_exp2f(x);
#else
    return exp2f(x);
#endif
}
__device__ __forceinline__ float flog2(float x) {
#if __has_builtin(__builtin_amdgcn_logf)
    return __builtin_amdgcn_logf(x);   // v_log_f32 = log2
#else
    return log2f(x);
#endif
}

// logsumexp in base-2 units: lse22(a,b) = log2(2^a + 2^b)
__device__ __forceinline__ float lse22(float a, float b) {
    float m = fmaxf(a, b);
    float d = fminf(a, b) - m;   // <= 0
    return m + flog2(1.0f + fexp2(d));
}

// Streaming one-touch loads (inputs are L3-evicted by the harness's 576MiB
// ws poison fill every iteration anyway; nt keeps the stream out of L2 so
// gt/valid lines survive for the second chunk-block).
__device__ __forceinline__ vf4 ldnt4(const float* p) {
    return __builtin_nontemporal_load((const vf4*)p);
}

// Stage 1: per-block partials, NO atomics. part[q * NBG + gb], q in [0, NQ).
__global__ __launch_bounds__(256) void loss_part(
    const float* __restrict__ fp,     // (12,4,2,H,W)
    const float* __restrict__ ip,     // (12,4,4,H,W)
    const float* __restrict__ gt,     // (4,2,H,W)
    const float* __restrict__ valid,  // (4,1,H,W)
    float* __restrict__ part) {

    const int chunk = blockIdx.x & (NCH - 1);
    const int gb    = blockIdx.x >> 1;
    const int g  = gb * 256 + threadIdx.x;          // float4-group id, exact cover
    const int b  = g / (HWc / 4);
    const int hw = (g % (HWc / 4)) * 4;
    const int n0 = chunk * NSPC;

    const vf4 gx4 = *(const vf4*)(gt + ((size_t)b * 2 + 0) * HWc + hw);
    const vf4 gy4 = *(const vf4*)(gt + ((size_t)b * 2 + 1) * HWc + hw);
    const vf4 vv4 = *(const vf4*)(valid + (size_t)b * HWc + hw);

    float gxa[4] = {gx4.x, gx4.y, gx4.z, gx4.w};
    float gya[4] = {gy4.x, gy4.y, gy4.z, gy4.w};
    float vva[4] = {vv4.x, vv4.y, vv4.z, vv4.w};

    bool  m1[4];
    float mcnt = 0.0f;
#pragma unroll
    for (int j = 0; j < 4; ++j) {
        float mag = sqrtf(gxa[j] * gxa[j] + gya[j] * gya[j]);
        m1[j] = (mag < MAX_FLOW_C) && (vva[j] != 0.0f);
        mcnt += m1[j] ? 1.0f : 0.0f;
    }

    float s[NSPC];
    float c[NSPC];
#pragma unroll
    for (int k = 0; k < NSPC; ++k) { s[k] = 0.0f; c[k] = 0.0f; }

#pragma unroll
    for (int k = 0; k < NSPC; ++k) {
        const int n = n0 + k;
        const float* fbase = fp + ((size_t)(n * Bc + b) * 2) * HWc + hw;
        const float* ibase = ip + ((size_t)(n * Bc + b) * 4) * HWc + hw;

        const vf4 fx4 = ldnt4(fbase);
        const vf4 fy4 = ldnt4(fbase + HWc);
        const vf4 a04 = ldnt4(ibase);
        const vf4 a14 = ldnt4(ibase + HWc);
        const vf4 lb4 = ldnt4(ibase + 2 * (size_t)HWc);
        // info channel 3 never read: clip(x, 0, 0) == 0 identically.

        float fxa[4] = {fx4.x, fx4.y, fx4.z, fx4.w};
        float fya[4] = {fy4.x, fy4.y, fy4.z, fy4.w};
        float a0a[4] = {a04.x, a04.y, a04.z, a04.w};
        float a1a[4] = {a14.x, a14.y, a14.z, a14.w};
        float lba[4] = {lb4.x, lb4.y, lb4.z, lb4.w};

#pragma unroll
        for (int j = 0; j < 4; ++j) {
            // Base-2 units: X' = X*log2(e); nf = ln2 * nf'.
            float LB  = fminf(fmaxf(lba[j], 0.0f), 10.0f) * L2E_C;
            float e2  = fexp2(-LB);             // exp(-lb0), unscaled
            float A0  = a0a[j] * L2E_C;
            float A1  = a1a[j] * L2E_C;
            float lsa = lse22(A0, A1);
            float t10 = A0 - 1.0f - LB;
            float t11 = A1 - 1.0f;              // lb1 == 0
            float D0  = fabsf(gxa[j] - fxa[j]) * L2E_C;
            float D1  = fabsf(gya[j] - fya[j]) * L2E_C;

            float nf0 = lsa - lse22(t10 - D0 * e2, t11 - D0);
            float nf1 = lsa - lse22(t10 - D1 * e2, t11 - D1);

            bool ok0 = m1[j] && isfinite(nf0);
            bool ok1 = m1[j] && isfinite(nf1);
            s[k] += ok0 ? nf0 : 0.0f;
            c[k] += ok0 ? 1.0f : 0.0f;
            s[k] += ok1 ? nf1 : 0.0f;
            c[k] += ok1 ? 1.0f : 0.0f;
        }
    }

    // ---- reduction: wave shuffle -> LDS -> plain stores (no atomics) ----
#pragma unroll
    for (int k = 0; k < NSPC; ++k) {
        for (int off = 32; off > 0; off >>= 1) {
            s[k] += __shfl_down(s[k], off);
            c[k] += __shfl_down(c[k], off);
        }
    }
    for (int off = 32; off > 0; off >>= 1) mcnt += __shfl_down(mcnt, off);

    __shared__ float red[4][2 * NSPC + 1];
    const int lane = threadIdx.x & 63;
    const int wid  = threadIdx.x >> 6;
    if (lane == 0) {
#pragma unroll
        for (int k = 0; k < NSPC; ++k) {
            red[wid][k]        = s[k];
            red[wid][NSPC + k] = c[k];
        }
        red[wid][2 * NSPC] = mcnt;
    }
    __syncthreads();
    if (threadIdx.x < 2 * NSPC + 1) {
        float v = red[0][threadIdx.x] + red[1][threadIdx.x] +
                  red[2][threadIdx.x] + red[3][threadIdx.x];
        int q;
        if (threadIdx.x < NSPC)           q = n0 + threadIdx.x;             // sums 0..11
        else if (threadIdx.x < 2 * NSPC)  q = 12 + n0 + threadIdx.x - NSPC; // counts 12..23
        else                              q = 24;                           // mcnt
        if (q != 24 || chunk == 0)        // q=24 written by chunk-0 blocks only
            part[(size_t)q * NBG + gb] = v;
    }
    // Every part[] slot is written every launch -> no zero-init needed.
}

// Stage 2+3 fused: one block reduces 25 x 768 partials and assembles the
// loss.  1024 threads = 16 waves: q-reductions finish in 2 wave-passes.
// Saves one dispatch (+its launch gap) vs the reduce+final pair.
__global__ __launch_bounds__(1024) void loss_tail(
    const float* __restrict__ part, float* __restrict__ out) {
    __shared__ float sq[NQ];
    const int lane = threadIdx.x & 63;
    const int wid  = threadIdx.x >> 6;   // 0..15
    for (int q = wid; q < NQ; q += 16) {
        const float* p = part + (size_t)q * NBG;
        float v = 0.0f;
        for (int i = lane; i < NBG; i += 64) v += p[i];   // 12 iters
        for (int off = 32; off > 0; off >>= 1) v += __shfl_down(v, off);
        if (lane == 0) sq[q] = v;
    }
    __syncthreads();
    if (threadIdx.x == 0) {
        float loss = 0.0f;
#pragma unroll
        for (int n = 0; n < NP; ++n)
            loss += LOG2_C * sq[n] / fmaxf(sq[12 + n], 1.0f);
        float mean_mask = sq[24] / (float)Pc;
        out[0] = (mean_mask < 0.25f) ? 0.0f : loss;
    }
}

extern "C" void kernel_launch(void* const* d_in, const int* in_sizes, int n_in,
                              void* d_out, int out_size, void* d_ws, size_t ws_size,
                              hipStream_t stream) {
    const float* fp    = (const float*)d_in[0];
    const float* ip    = (const float*)d_in[1];
    const float* gt    = (const float*)d_in[2];
    const float* valid = (const float*)d_in[3];
    float* part = (float*)d_ws;                    // NQ * NBG floats

    loss_part<<<NBG * NCH, 256, 0, stream>>>(fp, ip, gt, valid, part);
    loss_tail<<<1, 1024, 0, stream>>>(part, (float*)d_out);
}

// Round 3
// 252.209 us; speedup vs baseline: 1.0476x; 1.0048x over previous
//
#include <hip/hip_runtime.h>
#include <math.h>

// Problem constants
#define Hc 384
#define Wc 512
#define Bc 4
#define NP 12
#define HWc (Hc * Wc)        // 196608
#define Pc (Bc * HWc)        // 786432
#define MAX_FLOW_C 443.40500673763256f   // sqrt(384*512)
#define LOG2_C 0.69314718055994530942f   // ln(2)
#define L2E_C  1.44269504088896340736f   // log2(e)

// R2 post-mortem: body identical to the proven r0 kernel (2x6, no min-wave
// pin).  Only change: chunk-major block ordering.  With the old 1-D grid a
// pixel-group's two chunk-blocks were consecutive blockIdx -> round-robin
// onto DIFFERENT XCDs, so chunk 1 re-fetched gt/valid from HBM (9.4 MB).
// Chunk-major (dim3(NBG,NCH)) puts the pair 768 dispatches apart: 768%8==0
// -> SAME XCD, and the per-XCD gt/valid slice (~1.2 MB) fits 4 MiB L2 and
// survives because fp/ip streams are nontemporal (no L2 allocation).
#define NCH 2    // step chunks (blockIdx.y)
#define NSPC 6   // steps per chunk (NCH*NSPC == NP)
#define NBG 768  // pixel-group blocks (Pc/4/256)
#define NQ 25    // 12 sums + 12 counts + mask-count

typedef float vf4 __attribute__((ext_vector_type(4)));

__device__ __forceinline__ float fexp2(float x) {
#if __has_builtin(__builtin_amdgcn_exp2f)
    return __builtin_amdgcn_exp2f(x);
#else
    return exp2f(x);
#endif
}
__device__ __forceinline__ float flog2(float x) {
#if __has_builtin(__builtin_amdgcn_logf)
    return __builtin_amdgcn_logf(x);   // v_log_f32 = log2
#else
    return log2f(x);
#endif
}

// logsumexp in base-2 units: lse22(a,b) = log2(2^a + 2^b)
__device__ __forceinline__ float lse22(float a, float b) {
    float m = fmaxf(a, b);
    float d = fminf(a, b) - m;   // <= 0
    return m + flog2(1.0f + fexp2(d));
}

// Streaming one-touch loads for fp/ip only (nt = no L2 allocation, so the
// L2 keeps gt/valid lines alive for the chunk-1 blocks on the same XCD).
__device__ __forceinline__ vf4 ldnt4(const float* p) {
    return __builtin_nontemporal_load((const vf4*)p);
}

// Stage 1: per-block partials, NO atomics. part[q * NBG + gb], q in [0, NQ).
__global__ __launch_bounds__(256) void loss_part(
    const float* __restrict__ fp,     // (12,4,2,H,W)
    const float* __restrict__ ip,     // (12,4,4,H,W)
    const float* __restrict__ gt,     // (4,2,H,W)
    const float* __restrict__ valid,  // (4,1,H,W)
    float* __restrict__ part) {

    const int chunk = blockIdx.y;                   // 0..NCH-1  (chunk-major)
    const int gb    = blockIdx.x;                   // 0..NBG-1
    const int g  = gb * 256 + threadIdx.x;          // float4-group id, exact cover
    const int b  = g / (HWc / 4);
    const int hw = (g % (HWc / 4)) * 4;
    const int n0 = chunk * NSPC;

    const vf4 gx4 = *(const vf4*)(gt + ((size_t)b * 2 + 0) * HWc + hw);
    const vf4 gy4 = *(const vf4*)(gt + ((size_t)b * 2 + 1) * HWc + hw);
    const vf4 vv4 = *(const vf4*)(valid + (size_t)b * HWc + hw);

    float gxa[4] = {gx4.x, gx4.y, gx4.z, gx4.w};
    float gya[4] = {gy4.x, gy4.y, gy4.z, gy4.w};
    float vva[4] = {vv4.x, vv4.y, vv4.z, vv4.w};

    bool  m1[4];
    float mcnt = 0.0f;
#pragma unroll
    for (int j = 0; j < 4; ++j) {
        float mag = sqrtf(gxa[j] * gxa[j] + gya[j] * gya[j]);
        m1[j] = (mag < MAX_FLOW_C) && (vva[j] != 0.0f);
        mcnt += m1[j] ? 1.0f : 0.0f;
    }

    float s[NSPC];
    float c[NSPC];
#pragma unroll
    for (int k = 0; k < NSPC; ++k) { s[k] = 0.0f; c[k] = 0.0f; }

#pragma unroll
    for (int k = 0; k < NSPC; ++k) {
        const int n = n0 + k;
        const float* fbase = fp + ((size_t)(n * Bc + b) * 2) * HWc + hw;
        const float* ibase = ip + ((size_t)(n * Bc + b) * 4) * HWc + hw;

        const vf4 fx4 = ldnt4(fbase);
        const vf4 fy4 = ldnt4(fbase + HWc);
        const vf4 a04 = ldnt4(ibase);
        const vf4 a14 = ldnt4(ibase + HWc);
        const vf4 lb4 = ldnt4(ibase + 2 * (size_t)HWc);
        // info channel 3 never read: clip(x, 0, 0) == 0 identically.

        float fxa[4] = {fx4.x, fx4.y, fx4.z, fx4.w};
        float fya[4] = {fy4.x, fy4.y, fy4.z, fy4.w};
        float a0a[4] = {a04.x, a04.y, a04.z, a04.w};
        float a1a[4] = {a14.x, a14.y, a14.z, a14.w};
        float lba[4] = {lb4.x, lb4.y, lb4.z, lb4.w};

#pragma unroll
        for (int j = 0; j < 4; ++j) {
            // Base-2 units: X' = X*log2(e); nf = ln2 * nf'.
            float LB  = fminf(fmaxf(lba[j], 0.0f), 10.0f) * L2E_C;
            float e2  = fexp2(-LB);             // exp(-lb0), unscaled
            float A0  = a0a[j] * L2E_C;
            float A1  = a1a[j] * L2E_C;
            float lsa = lse22(A0, A1);
            float t10 = A0 - 1.0f - LB;
            float t11 = A1 - 1.0f;              // lb1 == 0
            float D0  = fabsf(gxa[j] - fxa[j]) * L2E_C;
            float D1  = fabsf(gya[j] - fya[j]) * L2E_C;

            float nf0 = lsa - lse22(t10 - D0 * e2, t11 - D0);
            float nf1 = lsa - lse22(t10 - D1 * e2, t11 - D1);

            bool ok0 = m1[j] && isfinite(nf0);
            bool ok1 = m1[j] && isfinite(nf1);
            s[k] += ok0 ? nf0 : 0.0f;
            c[k] += ok0 ? 1.0f : 0.0f;
            s[k] += ok1 ? nf1 : 0.0f;
            c[k] += ok1 ? 1.0f : 0.0f;
        }
    }

    // ---- reduction: wave shuffle -> LDS -> plain stores (no atomics) ----
#pragma unroll
    for (int k = 0; k < NSPC; ++k) {
        for (int off = 32; off > 0; off >>= 1) {
            s[k] += __shfl_down(s[k], off);
            c[k] += __shfl_down(c[k], off);
        }
    }
    for (int off = 32; off > 0; off >>= 1) mcnt += __shfl_down(mcnt, off);

    __shared__ float red[4][2 * NSPC + 1];
    const int lane = threadIdx.x & 63;
    const int wid  = threadIdx.x >> 6;
    if (lane == 0) {
#pragma unroll
        for (int k = 0; k < NSPC; ++k) {
            red[wid][k]        = s[k];
            red[wid][NSPC + k] = c[k];
        }
        red[wid][2 * NSPC] = mcnt;
    }
    __syncthreads();
    if (threadIdx.x < 2 * NSPC + 1) {
        float v = red[0][threadIdx.x] + red[1][threadIdx.x] +
                  red[2][threadIdx.x] + red[3][threadIdx.x];
        int q;
        if (threadIdx.x < NSPC)           q = n0 + threadIdx.x;             // sums 0..11
        else if (threadIdx.x < 2 * NSPC)  q = 12 + n0 + threadIdx.x - NSPC; // counts 12..23
        else                              q = 24;                           // mcnt
        if (q != 24 || chunk == 0)        // q=24 written by chunk-0 blocks only
            part[(size_t)q * NBG + gb] = v;
    }
    // Every part[] slot is written every launch -> no zero-init needed.
}

// Stage 2+3 fused: one block reduces 25 x 768 partials and assembles the
// loss.  1024 threads = 16 waves: q-reductions finish in 2 wave-passes.
__global__ __launch_bounds__(1024) void loss_tail(
    const float* __restrict__ part, float* __restrict__ out) {
    __shared__ float sq[NQ];
    const int lane = threadIdx.x & 63;
    const int wid  = threadIdx.x >> 6;   // 0..15
    for (int q = wid; q < NQ; q += 16) {
        const float* p = part + (size_t)q * NBG;
        float v = 0.0f;
        for (int i = lane; i < NBG; i += 64) v += p[i];   // 12 iters
        for (int off = 32; off > 0; off >>= 1) v += __shfl_down(v, off);
        if (lane == 0) sq[q] = v;
    }
    __syncthreads();
    if (threadIdx.x == 0) {
        float loss = 0.0f;
#pragma unroll
        for (int n = 0; n < NP; ++n)
            loss += LOG2_C * sq[n] / fmaxf(sq[12 + n], 1.0f);
        float mean_mask = sq[24] / (float)Pc;
        out[0] = (mean_mask < 0.25f) ? 0.0f : loss;
    }
}

extern "C" void kernel_launch(void* const* d_in, const int* in_sizes, int n_in,
                              void* d_out, int out_size, void* d_ws, size_t ws_size,
                              hipStream_t stream) {
    const float* fp    = (const float*)d_in[0];
    const float* ip    = (const float*)d_in[1];
    const float* gt    = (const float*)d_in[2];
    const float* valid = (const float*)d_in[3];
    float* part = (float*)d_ws;                    // NQ * NBG floats

    loss_part<<<dim3(NBG, NCH), 256, 0, stream>>>(fp, ip, gt, valid, part);
    loss_tail<<<1, 1024, 0, stream>>>(part, (float*)d_out);
}